// Round 4
// baseline (460.168 us; speedup 1.0000x reference)
//
#include <hip/hip_runtime.h>
#include <stdint.h>

// B=4, N=M=4096, C=256
#define CAP 192   // max matches kept per row (lambda~10, Poisson tail => never hit)

typedef __attribute__((ext_vector_type(4))) float f32x4;
typedef __attribute__((ext_vector_type(8))) short bf16x8;

__device__ __forceinline__ float bf2f(ushort u) {
  return __uint_as_float(((unsigned)u) << 16);
}
__device__ __forceinline__ ushort f2bf(float f) {
  unsigned u = __float_as_uint(f);
  return (ushort)((u + 0x7fffu + ((u >> 16) & 1u)) >> 16);  // RNE
}
__device__ __forceinline__ float wredsum(float v) {
#pragma unroll
  for (int o = 32; o; o >>= 1) v += __shfl_xor(v, o);
  return v;
}

// ---------------- f32 -> bf16 converts ----------------
__global__ __launch_bounds__(256) void cvt_kernel(const float* __restrict__ s,
                                                  ushort* __restrict__ d, int n4) {
  int i = blockIdx.x * 256 + threadIdx.x;
  if (i < n4) {
    float4 v = *(const float4*)(s + (size_t)i * 4);
    ushort4 o = { f2bf(v.x), f2bf(v.y), f2bf(v.z), f2bf(v.w) };
    *(ushort4*)(d + (size_t)i * 4) = o;
  }
}

__global__ __launch_bounds__(256) void cvt4_kernel(
    const float* __restrict__ s0, const float* __restrict__ s1,
    const float* __restrict__ s2, const float* __restrict__ s3,
    ushort* __restrict__ d0, ushort* __restrict__ d1,
    ushort* __restrict__ d2, ushort* __restrict__ d3) {
  int seg = blockIdx.x >> 6;  // 64 blocks per 65536-elem segment
  int i = ((blockIdx.x & 63) * 256 + threadIdx.x) * 4;
  const float* s = (seg == 0) ? s0 : (seg == 1) ? s1 : (seg == 2) ? s2 : s3;
  ushort* d = (seg == 0) ? d0 : (seg == 1) ? d1 : (seg == 2) ? d2 : d3;
  float4 v = *(const float4*)(s + i);
  ushort4 o = { f2bf(v.x), f2bf(v.y), f2bf(v.z), f2bf(v.w) };
  *(ushort4*)(d + i) = o;
}

// ---------------- GEMM body: Y[r,o] = sum_c A[r,c]*W[o,c] + bias[o] ----------------
// A bf16 [16384,256], W bf16 [256,256] row-major [out,in]
template <typename OutT>
__device__ __forceinline__ void gemm_body(const ushort* __restrict__ A,
                                          const ushort* __restrict__ W,
                                          const float* __restrict__ bias,
                                          OutT* __restrict__ Y, int blk,
                                          ushort* As, ushort* Bs) {
  int tid = threadIdx.x;
  int lane = tid & 63, wid = tid >> 6;
  int bm = blk >> 1, bn = blk & 1;
  int r0 = bm * 128, c0 = bn * 128;
  int wr = wid >> 1, wc = wid & 1;
  f32x4 acc[4][4] = {};
  for (int k0 = 0; k0 < 256; k0 += 32) {
    __syncthreads();
#pragma unroll
    for (int p = 0; p < 2; ++p) {
      int u = p * 2048 + tid * 8;
      int row = u >> 5, col = u & 31;
      *(bf16x8*)&As[u] = *(const bf16x8*)(A + (size_t)(r0 + row) * 256 + k0 + col);
      *(bf16x8*)&Bs[u] = *(const bf16x8*)(W + (size_t)(c0 + row) * 256 + k0 + col);
    }
    __syncthreads();
    bf16x8 af[4], bfr[4];
    int rsel = lane & 15, ksel = (lane >> 4) * 8;
#pragma unroll
    for (int m = 0; m < 4; ++m)
      af[m] = *(bf16x8*)&As[(wr * 64 + m * 16 + rsel) * 32 + ksel];
#pragma unroll
    for (int n = 0; n < 4; ++n)
      bfr[n] = *(bf16x8*)&Bs[(wc * 64 + n * 16 + rsel) * 32 + ksel];
#pragma unroll
    for (int m = 0; m < 4; ++m)
#pragma unroll
      for (int n = 0; n < 4; ++n)
        acc[m][n] = __builtin_amdgcn_mfma_f32_16x16x32_bf16(af[m], bfr[n], acc[m][n], 0, 0, 0);
  }
  int rbase = r0 + wr * 64 + ((lane >> 4) * 4);
  int cbase = c0 + wc * 64 + (lane & 15);
#pragma unroll
  for (int n = 0; n < 4; ++n) {
    float bv = bias[cbase + n * 16];
#pragma unroll
    for (int m = 0; m < 4; ++m) {
#pragma unroll
      for (int j = 0; j < 4; ++j) {
        float v = acc[m][n][j] + bv;
        size_t idx = (size_t)(rbase + m * 16 + j) * 256 + (cbase + n * 16);
        if constexpr (sizeof(OutT) == 2) Y[idx] = (OutT)f2bf(v);
        else Y[idx] = (OutT)v;
      }
    }
  }
}

// fused Q/K/V projection: 768 blocks (3 GEMMs x 256)
__global__ __launch_bounds__(256, 2) void gemm3(
    const ushort* __restrict__ Xl, const ushort* __restrict__ Xr,
    const ushort* __restrict__ Wqb, const ushort* __restrict__ Wkb,
    const ushort* __restrict__ Wvb, const float* __restrict__ bq,
    const float* __restrict__ bk, const float* __restrict__ bv,
    ushort* __restrict__ Qb, ushort* __restrict__ Kb, ushort* __restrict__ Vb) {
  __shared__ __align__(16) ushort As[128 * 32];
  __shared__ __align__(16) ushort Bs[128 * 32];
  int which = blockIdx.x >> 8;
  int blk = blockIdx.x & 255;
  const ushort* A = (which == 0) ? Xl : Xr;
  const ushort* W = (which == 0) ? Wqb : (which == 1) ? Wkb : Wvb;
  const float* bias = (which == 0) ? bq : (which == 1) ? bk : bv;
  ushort* Y = (which == 0) ? Qb : (which == 1) ? Kb : Vb;
  gemm_body<ushort>(A, W, bias, Y, blk, As, Bs);
}

__global__ __launch_bounds__(256, 2) void gemm_out(const ushort* __restrict__ A,
                                                   const ushort* __restrict__ W,
                                                   const float* __restrict__ bias,
                                                   float* __restrict__ Y) {
  __shared__ __align__(16) ushort As[128 * 32];
  __shared__ __align__(16) ushort Bs[128 * 32];
  gemm_body<float>(A, W, bias, Y, blockIdx.x, As, Bs);
}

// ---------------- column sums of nodes_R (f32) + u-sums of kpts_R ----------------
__global__ __launch_bounds__(256) void sum_nodes(const float* __restrict__ nodesR,
                                                 const float* __restrict__ kptsR,
                                                 float* __restrict__ S,
                                                 float* __restrict__ sumU) {
  int b = blockIdx.x >> 4, ch = blockIdx.x & 15;
  int t = threadIdx.x;
  int c4 = (t & 63) * 4;
  int r0 = b * 4096 + ch * 256 + (t >> 6);
  float4 acc = {0.f, 0.f, 0.f, 0.f};
  for (int k = 0; k < 64; ++k) {
    float4 v = *(const float4*)(nodesR + (size_t)(r0 + k * 4) * 256 + c4);
    acc.x += v.x; acc.y += v.y; acc.z += v.z; acc.w += v.w;
  }
  __shared__ float4 red[256];
  red[t] = acc;
  float u = kptsR[(size_t)(b * 4096 + ch * 256 + t) * 2];
  u = wredsum(u);
  __shared__ float ured[4];
  if ((t & 63) == 0) ured[t >> 6] = u;
  __syncthreads();
  if (t < 64) {
    float4 x = red[t], y = red[t + 64], z = red[t + 128], w = red[t + 192];
    atomicAdd(&S[b * 256 + c4 + 0], x.x + y.x + z.x + w.x);
    atomicAdd(&S[b * 256 + c4 + 1], x.y + y.y + z.y + w.y);
    atomicAdd(&S[b * 256 + c4 + 2], x.z + y.z + z.z + w.z);
    atomicAdd(&S[b * 256 + c4 + 3], x.w + y.w + z.w + w.w);
  }
  if (t == 0) atomicAdd(&sumU[b], ured[0] + ured[1] + ured[2] + ured[3]);
}

// meanV[b][c] = (S[b] . Wv[c,:]) / 4096 + bv[c];  meanU[b] = sumU[b]/4096
__global__ __launch_bounds__(256) void proj_mean(const float* __restrict__ S,
                                                 const float* __restrict__ sumU,
                                                 const float* __restrict__ Wv,
                                                 const float* __restrict__ bv,
                                                 ushort* __restrict__ meanVb,
                                                 float* __restrict__ meanU) {
  int b = blockIdx.x, c = threadIdx.x;
  const float* s = S + b * 256;
  float acc = 0.f;
  for (int k = 0; k < 256; k += 4) {
    float4 w = *(const float4*)(Wv + (size_t)c * 256 + k);
    acc += s[k] * w.x + s[k + 1] * w.y + s[k + 2] * w.z + s[k + 3] * w.w;
  }
  float mv = acc * (1.f / 4096.f) + bv[c];
  meanVb[b * 256 + c] = f2bf(mv);
  if (c == 0) meanU[b] = sumU[b] * (1.f / 4096.f);
}

// ---------------- wave-per-row sparse attention ----------------
__global__ __launch_bounds__(512, 2) void attn_rows(
    const float* __restrict__ kptsL, const float* __restrict__ kptsR,
    const ushort* __restrict__ Qb, const ushort* __restrict__ Kb,
    const ushort* __restrict__ Vb, const float* __restrict__ meanU,
    const ushort* __restrict__ meanVb, float* __restrict__ disp_out,
    float* __restrict__ conf_out, ushort* __restrict__ matched,
    int* __restrict__ rowcnt, int2* __restrict__ rowlist) {
  __shared__ float2 kR[4096];
  __shared__ int bufM[8][CAP];
  __shared__ float bufD[8][CAP];
  __shared__ float bufS[8][CAP];
  int tid = threadIdx.x, lane = tid & 63, wid = tid >> 6;
  int b = blockIdx.x >> 9;
  int n = ((blockIdx.x & 511) << 3) + wid;
  int row = (b << 12) + n;
  int bb = b << 12;
  const float2* kRsrc = (const float2*)kptsR + (size_t)bb;
  for (int i = tid; i < 4096; i += 512) kR[i] = kRsrc[i];
  __syncthreads();
  float2 kL = ((const float2*)kptsL)[(size_t)row];
  ushort4 qv = *(const ushort4*)(Qb + (size_t)row * 256 + lane * 4);
  float q0 = bf2f(qv.x), q1 = bf2f(qv.y), q2 = bf2f(qv.z), q3 = bf2f(qv.w);

  // ---- mask scan: popcount-prefix hit compaction ----
  int cnt = 0;
  for (int m0 = 0; m0 < 4096; m0 += 64) {
    float2 kr = kR[m0 + lane];
    float dv = fabsf(kL.y - kr.y);
    float du = kL.x - kr.x;
    bool hit = (dv < 3.0f) && (du > 0.0f) && (du < 192.0f);
    unsigned long long bal = __ballot(hit);
    if (bal) {
      if (hit) {
        int pos = cnt + (int)__popcll(bal & ((1ull << lane) - 1ull));
        if (pos < CAP) { bufM[wid][pos] = m0 + lane; bufD[wid][pos] = du; }
      }
      cnt += (int)__popcll(bal);
    }
  }
  if (cnt > CAP) cnt = CAP;

  float conf, disp;
  if (cnt == 0) {
    conf = 0.f;
    disp = kL.x - meanU[b];
    if (lane == 0) rowcnt[row] = 0;
    ushort4 st = *(const ushort4*)(meanVb + b * 256 + lane * 4);
    *(ushort4*)(matched + (size_t)row * 256 + lane * 4) = st;
  } else {
    // ---- QK^T for hits (2-way unrolled wave-cooperative dots) ----
    float mx = -1e30f;
    int i = 0;
    for (; i + 1 < cnt; i += 2) {
      int ma = bufM[wid][i], mb = bufM[wid][i + 1];
      ushort4 ka = *(const ushort4*)(Kb + ((size_t)(bb + ma)) * 256 + lane * 4);
      ushort4 kb2 = *(const ushort4*)(Kb + ((size_t)(bb + mb)) * 256 + lane * 4);
      float pa = q0 * bf2f(ka.x) + q1 * bf2f(ka.y) + q2 * bf2f(ka.z) + q3 * bf2f(ka.w);
      float pb = q0 * bf2f(kb2.x) + q1 * bf2f(kb2.y) + q2 * bf2f(kb2.z) + q3 * bf2f(kb2.w);
#pragma unroll
      for (int o = 32; o; o >>= 1) {
        pa += __shfl_xor(pa, o);
        pb += __shfl_xor(pb, o);
      }
      float sa = pa * 0.0625f, sb = pb * 0.0625f;
      if (lane == 0) { bufS[wid][i] = sa; bufS[wid][i + 1] = sb; }
      mx = fmaxf(mx, fmaxf(sa, sb));
    }
    if (i < cnt) {
      int ma = bufM[wid][i];
      ushort4 ka = *(const ushort4*)(Kb + ((size_t)(bb + ma)) * 256 + lane * 4);
      float pa = q0 * bf2f(ka.x) + q1 * bf2f(ka.y) + q2 * bf2f(ka.z) + q3 * bf2f(ka.w);
      pa = wredsum(pa);
      float sa = pa * 0.0625f;
      if (lane == 0) bufS[wid][i] = sa;
      mx = fmaxf(mx, sa);
    }
    // ---- softmax ----
    float psum = 0.f, pdisp = 0.f;
    for (int k = lane; k < cnt; k += 64) {
      float e = expf(bufS[wid][k] - mx);
      bufS[wid][k] = e;
      psum += e;
      pdisp += e * bufD[wid][k];
    }
    psum = wredsum(psum);
    pdisp = wredsum(pdisp);
    float inv = 1.f / psum;
    disp = pdisp * inv;
    conf = 1.f;
    for (int k = lane; k < cnt; k += 64) {
      int2 e;
      e.x = bufM[wid][k];
      e.y = __float_as_int(bufS[wid][k] * inv);
      rowlist[(size_t)row * CAP + k] = e;
    }
    if (lane == 0) rowcnt[row] = cnt;
    // ---- PV (2-way unrolled) ----
    float a0 = 0.f, a1 = 0.f, a2 = 0.f, a3 = 0.f;
    i = 0;
    for (; i + 1 < cnt; i += 2) {
      float wa = bufS[wid][i] * inv, wb = bufS[wid][i + 1] * inv;
      int ma = bufM[wid][i], mb = bufM[wid][i + 1];
      ushort4 va = *(const ushort4*)(Vb + ((size_t)(bb + ma)) * 256 + lane * 4);
      ushort4 vb2 = *(const ushort4*)(Vb + ((size_t)(bb + mb)) * 256 + lane * 4);
      a0 += wa * bf2f(va.x) + wb * bf2f(vb2.x);
      a1 += wa * bf2f(va.y) + wb * bf2f(vb2.y);
      a2 += wa * bf2f(va.z) + wb * bf2f(vb2.z);
      a3 += wa * bf2f(va.w) + wb * bf2f(vb2.w);
    }
    if (i < cnt) {
      float wa = bufS[wid][i] * inv;
      int ma = bufM[wid][i];
      ushort4 va = *(const ushort4*)(Vb + ((size_t)(bb + ma)) * 256 + lane * 4);
      a0 += wa * bf2f(va.x); a1 += wa * bf2f(va.y);
      a2 += wa * bf2f(va.z); a3 += wa * bf2f(va.w);
    }
    ushort4 st = { f2bf(a0), f2bf(a1), f2bf(a2), f2bf(a3) };
    *(ushort4*)(matched + (size_t)row * 256 + lane * 4) = st;
  }
  if (lane == 0) { disp_out[row] = disp; conf_out[row] = conf; }
}

// ---------------- attn_weights: pure streaming fill ----------------
__global__ __launch_bounds__(256) void fill_attn(const int* __restrict__ rowcnt,
                                                 float* __restrict__ attn) {
  int r0 = blockIdx.x * 8;
  int tid = threadIdx.x;
#pragma unroll
  for (int r = 0; r < 8; ++r) {
    int row = r0 + r;
    float fill = (rowcnt[row] == 0) ? (1.f / 4096.f) : 0.f;
    f32x4 fv = { fill, fill, fill, fill };
    f32x4* dst = (f32x4*)(attn + (size_t)row * 4096);
#pragma unroll
    for (int j = 0; j < 4; ++j)
      __builtin_nontemporal_store(fv, dst + j * 256 + tid);
  }
}

__global__ __launch_bounds__(256) void scatter_attn(const int* __restrict__ rowcnt,
                                                    const int2* __restrict__ rowlist,
                                                    float* __restrict__ attn) {
  int row = blockIdx.x * 4 + (threadIdx.x >> 6);
  int lane = threadIdx.x & 63;
  int cnt = rowcnt[row];
  for (int i = lane; i < cnt; i += 64) {
    int2 e = rowlist[(size_t)row * CAP + i];
    attn[(size_t)row * 4096 + e.x] = __int_as_float(e.y);
  }
}

extern "C" void kernel_launch(void* const* d_in, const int* in_sizes, int n_in,
                              void* d_out, int out_size, void* d_ws, size_t ws_size,
                              hipStream_t stream) {
  const float* nodes_L = (const float*)d_in[0];
  const float* nodes_R = (const float*)d_in[1];
  const float* kpts_L = (const float*)d_in[2];
  const float* kpts_R = (const float*)d_in[3];
  const float* Wq = (const float*)d_in[4];
  const float* bq = (const float*)d_in[5];
  const float* Wk = (const float*)d_in[6];
  const float* bk = (const float*)d_in[7];
  const float* Wv = (const float*)d_in[8];
  const float* bv = (const float*)d_in[9];
  const float* Wm = (const float*)d_in[10];
  const float* bm = (const float*)d_in[11];

  float* out = (float*)d_out;            // [4,4096,256]
  float* disp = out + 4194304;           // [4,4096,1]
  float* conf = disp + 16384;            // [4,4096,1]
  float* attn = conf + 16384;            // [4,4096,4096]

  char* ws = (char*)d_ws;
  ushort* Xl = (ushort*)(ws + 0);                 // 8 MB
  ushort* Xr = (ushort*)(ws + 8388608);           // 8 MB
  ushort* Wqb = (ushort*)(ws + 16777216);
  ushort* Wkb = Wqb + 65536;
  ushort* Wvb = Wkb + 65536;
  ushort* Wmb = Wvb + 65536;
  ushort* Qb = (ushort*)(ws + 17301504);          // 8 MB
  ushort* Kb = (ushort*)(ws + 25690112);          // 8 MB
  ushort* Vb = (ushort*)(ws + 34078720);          // 8 MB
  ushort* matched = (ushort*)(ws + 42467328);     // 8 MB
  float* S = (float*)(ws + 50855936);             // 1024 f32 column sums
  float* sumU = (float*)(ws + 50860032);          // 4 f32
  float* meanU = (float*)(ws + 50860096);         // 4 f32
  ushort* meanVb = (ushort*)(ws + 50860160);      // 1024 bf16
  int* rowcnt = (int*)(ws + 50864128);            // 64 KB
  int2* rowlist = (int2*)(ws + 50929664);         // 24 MB

  (void)hipMemsetAsync(S, 0, 4096 + 64, stream);  // zero S + sumU
  cvt_kernel<<<4096, 256, 0, stream>>>(nodes_L, Xl, 1048576);
  cvt_kernel<<<4096, 256, 0, stream>>>(nodes_R, Xr, 1048576);
  cvt4_kernel<<<256, 256, 0, stream>>>(Wq, Wk, Wv, Wm, Wqb, Wkb, Wvb, Wmb);
  sum_nodes<<<64, 256, 0, stream>>>(nodes_R, kpts_R, S, sumU);
  gemm3<<<768, 256, 0, stream>>>(Xl, Xr, Wqb, Wkb, Wvb, bq, bk, bv, Qb, Kb, Vb);
  proj_mean<<<4, 256, 0, stream>>>(S, sumU, Wv, bv, meanVb, meanU);
  attn_rows<<<2048, 512, 0, stream>>>(kpts_L, kpts_R, Qb, Kb, Vb, meanU, meanVb,
                                      disp, conf, matched, rowcnt, rowlist);
  fill_attn<<<2048, 256, 0, stream>>>(rowcnt, attn);
  scatter_attn<<<4096, 256, 0, stream>>>(rowcnt, rowlist, attn);
  gemm_out<<<256, 256, 0, stream>>>(matched, Wmb, bm, out);
}